// Round 8
// baseline (2558.072 us; speedup 1.0000x reference)
//
#include <hip/hip_runtime.h>

#define BATCH 4
#define NPTS 8192
#define MPTS 2048
#define CIN 128
#define CO 256
#define KS 32
#define ND 32
#define HALF 128

typedef unsigned int u32;
typedef unsigned long long u64;
typedef float f32x2 __attribute__((ext_vector_type(2)));

// DPP ctrl codes
#define DPPC_QUAD_XOR1 0xB1
#define DPPC_QUAD_XOR2 0x4E
#define DPPC_ROW_MIRROR 0x140
#define DPPC_ROW_HALF_MIRROR 0x141
#define DPPC_ROW_BCAST15 0x142
#define DPPC_ROW_BCAST31 0x143

template<int CTRL>
__device__ __forceinline__ float dpp_max(float v) {
    int o = __builtin_amdgcn_update_dpp(__float_as_int(-1e30f), __float_as_int(v),
                                        CTRL, 0xF, 0xF, false);
    return fmaxf(v, __int_as_float(o));
}
__device__ __forceinline__ float wave_max_f32(float v) {
    v = dpp_max<DPPC_QUAD_XOR1>(v);
    v = dpp_max<DPPC_QUAD_XOR2>(v);
    v = dpp_max<DPPC_ROW_HALF_MIRROR>(v);
    v = dpp_max<DPPC_ROW_MIRROR>(v);
    v = dpp_max<DPPC_ROW_BCAST15>(v);
    v = dpp_max<DPPC_ROW_BCAST31>(v);
    return __int_as_float(__builtin_amdgcn_readlane(__float_as_int(v), 63));
}

// packed fp32 (VOP3P): per-component IEEE ops -> bit-identical to scalar
__device__ __forceinline__ f32x2 pk_add(f32x2 a, f32x2 b) {
    f32x2 r;
    asm("v_pk_add_f32 %0, %1, %2" : "=v"(r) : "v"(a), "v"(b));
    return r;
}
__device__ __forceinline__ f32x2 pk_mul(f32x2 a, f32x2 b) {
    f32x2 r;
    asm("v_pk_mul_f32 %0, %1, %2" : "=v"(r) : "v"(a), "v"(b));
    return r;
}

struct FeatSmem {
    float sdx[KS], sdy[KS], sdz[KS];
    float ltm[ND], lfi[CIN], lh[HALF];
    int swidx[4][KS];
    int scnt[4];
    int nb[KS], nbp[KS];
};

// =================== streaming mega-kernel (mode 3, proven R7) =================
// blocks 0..3: FPS + per-step progress publish (agent-scope atomics).
//   R8 change: dist loop uses PACKED fp32 (v_pk_add/mul) -- 2 points per
//   instruction, bit-identical rounding; dist-issue ~704 -> ~450 cyc/step.
//   Coord pairs packed once, pinned via asm (R2: allocator grants ~110 VGPR
//   under waves_per_eu(2,2)).
// blocks 4..1027: f1 precompute + completion publish.
// blocks 1028..5123: feat, 2 queries/block, spin-wait then acquire.
__global__
__attribute__((amdgpu_flat_work_group_size(512, 512), amdgpu_waves_per_eu(2, 2)))
void k_mega(
    const float* __restrict__ p, const float* __restrict__ f,
    const float* __restrict__ conv1_w, const float* __restrict__ conv1_b,
    const float* __restrict__ skip_w,  const float* __restrict__ skip_b,
    const float* __restrict__ bn1_g, const float* __restrict__ bn1_b,
    const float* __restrict__ bn1_m, const float* __restrict__ bn1_v,
    const float* __restrict__ dirv,  const float* __restrict__ de_w1,
    const float* __restrict__ de_g,  const float* __restrict__ de_bb,
    const float* __restrict__ de_m,  const float* __restrict__ de_v,
    const float* __restrict__ de_w2, const float* __restrict__ de_b2,
    float* __restrict__ out_newp, float* __restrict__ out_f,
    int* __restrict__ idx, float* __restrict__ f1t,
    int* prog, int* f1all) {
    __shared__ __align__(16) char smem_u[16640];
    if (blockIdx.x < 4) {
        // ---------------- FPS ----------------
        u64* wkey = (u64*)smem_u;              // [2][8]
        int b = blockIdx.x, t = threadIdx.x;
        int lane = t & 63, wid = t >> 6;
        int j0 = t * 16;
        const float* pb = p + (size_t)b * NPTS * 3;
        const float* pt = pb + t * 48;
        float px[16], py[16], pz[16];
#pragma unroll
        for (int c = 0; c < 4; ++c) {
            float4 q0 = *(const float4*)(pt + c * 12 + 0);
            float4 q1 = *(const float4*)(pt + c * 12 + 4);
            float4 q2 = *(const float4*)(pt + c * 12 + 8);
            px[c*4+0] = q0.x; py[c*4+0] = q0.y; pz[c*4+0] = q0.z;
            px[c*4+1] = q0.w; py[c*4+1] = q1.x; pz[c*4+1] = q1.y;
            px[c*4+2] = q1.z; py[c*4+2] = q1.w; pz[c*4+2] = q2.x;
            px[c*4+3] = q2.y; py[c*4+3] = q2.z; pz[c*4+3] = q2.w;
        }
        // pack into pairs (one-time) and pin -- packed ops need pair regs
        f32x2 px2[8], py2[8], pz2[8], dist2[8];
#pragma unroll
        for (int i = 0; i < 8; ++i) {
            px2[i].x = px[2*i]; px2[i].y = px[2*i+1];
            py2[i].x = py[2*i]; py2[i].y = py[2*i+1];
            pz2[i].x = pz[2*i]; pz2[i].y = pz[2*i+1];
        }
#pragma unroll
        for (int i = 0; i < 8; ++i) {
            asm volatile("" : "+v"(px2[i]), "+v"(py2[i]), "+v"(pz2[i]));
        }
#pragma unroll
        for (int i = 0; i < 8; ++i) { dist2[i].x = 1e10f; dist2[i].y = 1e10f; }
        float lx = pb[0], ly = pb[1], lz = pb[2];
        if (t == 0) {
            out_newp[(size_t)b * MPTS * 3 + 0] = lx;
            out_newp[(size_t)b * MPTS * 3 + 1] = ly;
            out_newp[(size_t)b * MPTS * 3 + 2] = lz;
            __hip_atomic_store(idx + b * MPTS, 0, __ATOMIC_RELAXED,
                               __HIP_MEMORY_SCOPE_AGENT);
        }
        for (int s = 1; s < MPTS; ++s) {
            int par = s & 1;
            // negated broadcast: px + (-lx) is IEEE-identical to px - lx
            f32x2 nlx2, nly2, nlz2;
            nlx2.x = -lx; nlx2.y = -lx;
            nly2.x = -ly; nly2.y = -ly;
            nlz2.x = -lz; nlz2.y = -lz;
            float bv = -1e30f; int bi = 0;
#pragma unroll
            for (int i = 0; i < 8; ++i) {
                // numpy-f32 order: (dx*dx + dy*dy) + dz*dz, per-component
                f32x2 dx = pk_add(px2[i], nlx2);
                f32x2 dy = pk_add(py2[i], nly2);
                f32x2 dz = pk_add(pz2[i], nlz2);
                f32x2 d  = pk_add(pk_add(pk_mul(dx, dx), pk_mul(dy, dy)),
                                  pk_mul(dz, dz));
                float nd0 = fminf(dist2[i].x, d.x);
                float nd1 = fminf(dist2[i].y, d.y);
                dist2[i].x = nd0;
                dist2[i].y = nd1;
                bool g0 = nd0 > bv;            // strict > keeps lowest index
                bi = g0 ? 2*i : bi;
                bv = fmaxf(bv, nd0);
                bool g1 = nd1 > bv;
                bi = g1 ? 2*i+1 : bi;
                bv = fmaxf(bv, nd1);
            }
            float gmw = wave_max_f32(bv);
            u64 mask = __ballot(bv == gmw);
            int first = __ffsll((long long)mask) - 1;
            if (lane == first) {
                wkey[par * 8 + wid] = ((u64)__float_as_uint(gmw) << 32)
                                    | (u64)(u32)(NPTS - 1 - (j0 + bi));
            }
            __syncthreads();                    // only barrier per step
            const u64* wk = wkey + par * 8;
            u64 k0 = wk[0], k1 = wk[1], k2 = wk[2], k3 = wk[3];
            u64 k4 = wk[4], k5 = wk[5], k6 = wk[6], k7 = wk[7];
            u64 m01 = k1 > k0 ? k1 : k0;
            u64 m23 = k3 > k2 ? k3 : k2;
            u64 m45 = k5 > k4 ? k5 : k4;
            u64 m67 = k7 > k6 ? k7 : k6;
            u64 m03 = m23 > m01 ? m23 : m01;
            u64 m47 = m67 > m45 ? m67 : m45;
            u64 best = m47 > m03 ? m47 : m03;
            int w0 = (NPTS - 1 - (int)(best & 0xFFFFFFFFull)) & (NPTS - 1);
            int w0s = __builtin_amdgcn_readfirstlane(w0);
            if (t == 0) {
                // publish progress for steps < s; vmcnt(0) waits only
                // ~1-step-old acks (already retired) -> effectively free
                asm volatile("s_waitcnt vmcnt(0)" ::: "memory");
                __hip_atomic_store(prog + b, s, __ATOMIC_RELAXED,
                                   __HIP_MEMORY_SCOPE_AGENT);
            }
            lx = pb[w0s * 3 + 0]; ly = pb[w0s * 3 + 1]; lz = pb[w0s * 3 + 2];
            if (t == 0) {
                out_newp[((size_t)b * MPTS + s) * 3 + 0] = lx;
                out_newp[((size_t)b * MPTS + s) * 3 + 1] = ly;
                out_newp[((size_t)b * MPTS + s) * 3 + 2] = lz;
                __hip_atomic_store(idx + b * MPTS + s, w0s, __ATOMIC_RELAXED,
                                   __HIP_MEMORY_SCOPE_AGENT);
            }
        }
        if (t == 0) {
            asm volatile("s_waitcnt vmcnt(0)" ::: "memory");
            __hip_atomic_store(prog + b, MPTS, __ATOMIC_RELAXED,
                               __HIP_MEMORY_SCOPE_AGENT);
        }
    } else if (blockIdx.x < 4 + 1024) {
        // ---------------- f1 precompute ----------------
        float* fT = (float*)smem_u;            // [k][j], 16 KB
        int blk = blockIdx.x - 4;
        int b = blk >> 8;
        int n0 = (blk & 255) << 5;
        int t = threadIdx.x;
        const float* fb = f + (size_t)b * CIN * NPTS;
        for (int e = t; e < CIN * 32; e += 512) {
            int k = e >> 5, j = e & 31;
            fT[e] = fb[(size_t)k * NPTS + n0 + j];
        }
        __syncthreads();
        int c = t & 255, jh = (t >> 8) << 4;
        float bias = conv1_b[c];
        float acc[16];
#pragma unroll
        for (int j = 0; j < 16; ++j) acc[j] = bias;
        const float4* wrow4 = (const float4*)(conv1_w + (size_t)c * CIN);
        const float4* fT4 = (const float4*)fT;
        for (int k4 = 0; k4 < 32; ++k4) {
            float4 wv = wrow4[k4];
#pragma unroll
            for (int sub = 0; sub < 4; ++sub) {
                float w = sub == 0 ? wv.x : sub == 1 ? wv.y : sub == 2 ? wv.z : wv.w;
                int k = k4 * 4 + sub;
                int base = (k * 32 + jh) >> 2;
                float4 a0 = fT4[base+0], a1 = fT4[base+1], a2 = fT4[base+2], a3 = fT4[base+3];
                acc[0]  = fmaf(w, a0.x, acc[0]);  acc[1]  = fmaf(w, a0.y, acc[1]);
                acc[2]  = fmaf(w, a0.z, acc[2]);  acc[3]  = fmaf(w, a0.w, acc[3]);
                acc[4]  = fmaf(w, a1.x, acc[4]);  acc[5]  = fmaf(w, a1.y, acc[5]);
                acc[6]  = fmaf(w, a1.z, acc[6]);  acc[7]  = fmaf(w, a1.w, acc[7]);
                acc[8]  = fmaf(w, a2.x, acc[8]);  acc[9]  = fmaf(w, a2.y, acc[9]);
                acc[10] = fmaf(w, a2.z, acc[10]); acc[11] = fmaf(w, a2.w, acc[11]);
                acc[12] = fmaf(w, a3.x, acc[12]); acc[13] = fmaf(w, a3.y, acc[13]);
                acc[14] = fmaf(w, a3.z, acc[14]); acc[15] = fmaf(w, a3.w, acc[15]);
            }
        }
        float* dst = f1t + ((size_t)b * NPTS + n0 + jh) * CO + c;
#pragma unroll
        for (int j = 0; j < 16; ++j) dst[(size_t)j * CO] = acc[j];
        __syncthreads();                       // all block's stores ack'd
        if (t == 0) {
            __threadfence();                   // push to coherent point
            atomicAdd(f1all, 1);               // device-scope, cross-XCD safe
        }
    } else {
        // ---------------- streaming feat: 2 queries per block ----------------
        int fb = (int)blockIdx.x - (4 + 1024);
        int m  = fb >> 1;
        int bA = (fb & 1) * 2;
        int t = threadIdx.x;
        if (t == 0) {
            int need = m + 1;
            for (int it = 0; it < (1 << 21); ++it) {
                if (__hip_atomic_load(prog + bA, __ATOMIC_RELAXED,
                                      __HIP_MEMORY_SCOPE_AGENT) >= need) break;
                __builtin_amdgcn_s_sleep(127);
            }
            for (int it = 0; it < (1 << 21); ++it) {
                if (__hip_atomic_load(prog + bA + 1, __ATOMIC_RELAXED,
                                      __HIP_MEMORY_SCOPE_AGENT) >= need) break;
                __builtin_amdgcn_s_sleep(127);
            }
            for (int it = 0; it < (1 << 21); ++it) {
                if (__hip_atomic_load(f1all, __ATOMIC_RELAXED,
                                      __HIP_MEMORY_SCOPE_AGENT) >= 1024) break;
                __builtin_amdgcn_s_sleep(127);
            }
            (void)__hip_atomic_load(prog + bA, __ATOMIC_ACQUIRE,
                                    __HIP_MEMORY_SCOPE_AGENT);
        }
        __syncthreads();
        int qi = t >> 8;                       // 0 or 1
        int tq = t & 255;
        int b  = bA + qi;
        FeatSmem* fs = ((FeatSmem*)smem_u) + qi;
        int lane = t & 63, wq = (t >> 6) & 3;
        const float* pb = p + (size_t)b * NPTS * 3;
        int i0 = idx[(size_t)b * MPTS + m] & (NPTS - 1);
        float qx = pb[i0 * 3 + 0], qy = pb[i0 * 3 + 1], qz = pb[i0 * 3 + 2];
        const float R2 = 0.1f * 0.1f;

        int cnt = 0;
        int seg = wq * 2048;
        for (int base = 0; base < 2048; base += 64) {
            int j = seg + base + lane;
            float dx = __fsub_rn(pb[j * 3 + 0], qx);
            float dy = __fsub_rn(pb[j * 3 + 1], qy);
            float dz = __fsub_rn(pb[j * 3 + 2], qz);
            float d2 = __fadd_rn(__fadd_rn(__fmul_rn(dx, dx), __fmul_rn(dy, dy)),
                                 __fmul_rn(dz, dz));
            bool hit = d2 < R2;
            u64 mask = __ballot(hit);
            if (hit) {
                int pos = cnt + __popcll(mask & ((1ull << lane) - 1ull));
                if (pos < KS) fs->swidx[wq][pos] = j;
            }
            cnt += __popcll(mask);
            if (cnt >= KS) break;
        }
        if (lane == 0) fs->scnt[wq] = cnt < KS ? cnt : KS;
        __syncthreads();
        int c0s = fs->scnt[0], c1s = fs->scnt[1], c2s = fs->scnt[2], c3s = fs->scnt[3];
        int st1 = c0s, st2 = c0s + c1s, st3 = c0s + c1s + c2s;
        int total = c0s + c1s + c2s + c3s; if (total > KS) total = KS;
        if (total < 1) total = 1;
        if (tq < 128) {
            int ww = tq >> 5, l = tq & 31;
            int stw = (ww == 0) ? 0 : (ww == 1) ? st1 : (ww == 2) ? st2 : st3;
            int cw  = (ww == 0) ? c0s : (ww == 1) ? c1s : (ww == 2) ? c2s : c3s;
            int gp = stw + l;
            if (l < cw && gp < KS) fs->nb[gp] = fs->swidx[ww][l];
        }
        __syncthreads();
        if (tq < KS) {
            int jk = fs->nb[tq < total ? tq : 0] & (NPTS - 1);
            fs->nbp[tq] = jk;
            float dx = pb[jk * 3 + 0] - qx;
            float dy = pb[jk * 3 + 1] - qy;
            float dz = pb[jk * 3 + 2] - qz;
            float nr = fmaxf(sqrtf(dx * dx + dy * dy + dz * dz), 1e-12f);
            fs->sdx[tq] = dx / nr; fs->sdy[tq] = dy / nr; fs->sdz[tq] = dz / nr;
        }
        if (tq >= 128) {
            fs->lfi[tq - 128] = f[((size_t)b * CIN + (tq - 128)) * NPTS + i0];
        }
        __syncthreads();
        if (tq < ND) {
            float ax = dirv[tq * 3], ay = dirv[tq * 3 + 1], az = dirv[tq * 3 + 2];
            float n = fmaxf(sqrtf(ax * ax + ay * ay + az * az), 1e-12f);
            float vx = ax / n, vy = ay / n, vz = az / n;
            float tm = -1e30f;
#pragma unroll
            for (int k = 0; k < KS; ++k)
                tm = fmaxf(tm, vx * fs->sdx[k] + vy * fs->sdy[k] + vz * fs->sdz[k]);
            fs->ltm[tq] = tm;
        }
        __syncthreads();

        int c = tq;
        const float* f1b = f1t + (size_t)b * NPTS * CO + c;
        float mx = -1e30f;
#pragma unroll 8
        for (int k = 0; k < KS; ++k) {
            mx = fmaxf(mx, f1b[(size_t)fs->nbp[k] * CO]);
        }
        float sc1 = bn1_g[c] / sqrtf(bn1_v[c] + 1e-5f);
        float o1 = (mx - bn1_m[c]) * sc1 + bn1_b[c];

        float idv = skip_b[c];
        {
            const float4* sr = (const float4*)(skip_w + (size_t)c * CIN);
#pragma unroll 8
            for (int r = 0; r < 32; ++r) {
                float4 v = sr[r];
                idv = fmaf(v.x, fs->lfi[r*4+0], fmaf(v.y, fs->lfi[r*4+1],
                      fmaf(v.z, fs->lfi[r*4+2], fmaf(v.w, fs->lfi[r*4+3], idv))));
            }
        }
        {
            int hc = c & (HALF - 1);
            const float4* d1 = (const float4*)(de_w1 + (size_t)hc * ND);
            float a = 0.0f;
#pragma unroll
            for (int r = 0; r < 8; ++r) {
                float4 v = d1[r];
                a = fmaf(v.x, fs->ltm[r*4+0], fmaf(v.y, fs->ltm[r*4+1],
                    fmaf(v.z, fs->ltm[r*4+2], fmaf(v.w, fs->ltm[r*4+3], a))));
            }
            float dsc = de_g[hc] / sqrtf(de_v[hc] + 1e-5f);
            float xb = (a - de_m[hc]) * dsc + de_bb[hc];
            float hv = 0.5f * xb * (1.0f + erff(xb * 0.70710678118654752440f));
            if (c < HALF) fs->lh[c] = hv;
        }
        __syncthreads();
        float pe = de_b2[c];
        {
            const float4* d2p = (const float4*)(de_w2 + (size_t)c * HALF);
#pragma unroll 8
            for (int r = 0; r < 32; ++r) {
                float4 v = d2p[r];
                pe = fmaf(v.x, fs->lh[r*4+0], fmaf(v.y, fs->lh[r*4+1],
                     fmaf(v.z, fs->lh[r*4+2], fmaf(v.w, fs->lh[r*4+3], pe))));
            }
        }
        out_f[((size_t)b * CO + c) * MPTS + m] = o1 + pe + idv;
    }
}

// =================== fallback kernels (modes 2/1/0, unchanged) =================
__global__ __launch_bounds__(512, 2) void k_fps_f1(
    const float* __restrict__ p, const float* __restrict__ f,
    const float* __restrict__ conv1_w, const float* __restrict__ conv1_b,
    float* __restrict__ out_newp, int* __restrict__ idx,
    float* __restrict__ f1t) {
    __shared__ __align__(16) char smem_u[33024];
    if (blockIdx.x < 4) {
        u64*   wkey = (u64*)smem_u;
        int*   sidx = (int*)(smem_u + 128);
        float* sx   = (float*)(smem_u + 128 + 4 * MPTS);
        float* sy   = sx + MPTS;
        float* sz   = sy + MPTS;
        int b = blockIdx.x, t = threadIdx.x;
        int lane = t & 63, wid = t >> 6;
        int j0 = t * 16;
        const float* pb = p + (size_t)b * NPTS * 3;
        const float* pt = pb + t * 48;
        float px[16], py[16], pz[16], dist[16];
#pragma unroll
        for (int c = 0; c < 4; ++c) {
            float4 q0 = *(const float4*)(pt + c * 12 + 0);
            float4 q1 = *(const float4*)(pt + c * 12 + 4);
            float4 q2 = *(const float4*)(pt + c * 12 + 8);
            px[c*4+0] = q0.x; py[c*4+0] = q0.y; pz[c*4+0] = q0.z;
            px[c*4+1] = q0.w; py[c*4+1] = q1.x; pz[c*4+1] = q1.y;
            px[c*4+2] = q1.z; py[c*4+2] = q1.w; pz[c*4+2] = q2.x;
            px[c*4+3] = q2.y; py[c*4+3] = q2.z; pz[c*4+3] = q2.w;
        }
#pragma unroll
        for (int i = 0; i < 16; ++i) dist[i] = 1e10f;
        float lx = pb[0], ly = pb[1], lz = pb[2];
        if (t == 0) { sidx[0] = 0; sx[0] = lx; sy[0] = ly; sz[0] = lz; }
        for (int s = 1; s < MPTS; ++s) {
            int par = s & 1;
            float bv = -1e30f; int bi = 0;
#pragma unroll
            for (int i = 0; i < 16; ++i) {
                float dx = __fsub_rn(px[i], lx);
                float dy = __fsub_rn(py[i], ly);
                float dz = __fsub_rn(pz[i], lz);
                float d  = __fadd_rn(__fadd_rn(__fmul_rn(dx, dx), __fmul_rn(dy, dy)),
                                     __fmul_rn(dz, dz));
                float nd = fminf(dist[i], d);
                dist[i] = nd;
                bool gt = nd > bv;
                bi = gt ? i : bi;
                bv = fmaxf(bv, nd);
            }
            float gmw = wave_max_f32(bv);
            u64 mask = __ballot(bv == gmw);
            int first = __ffsll((long long)mask) - 1;
            if (lane == first) {
                wkey[par * 8 + wid] = ((u64)__float_as_uint(gmw) << 32)
                                    | (u64)(u32)(NPTS - 1 - (j0 + bi));
            }
            __syncthreads();
            const u64* wk = wkey + par * 8;
            u64 k0 = wk[0], k1 = wk[1], k2 = wk[2], k3 = wk[3];
            u64 k4 = wk[4], k5 = wk[5], k6 = wk[6], k7 = wk[7];
            u64 m01 = k1 > k0 ? k1 : k0;
            u64 m23 = k3 > k2 ? k3 : k2;
            u64 m45 = k5 > k4 ? k5 : k4;
            u64 m67 = k7 > k6 ? k7 : k6;
            u64 m03 = m23 > m01 ? m23 : m01;
            u64 m47 = m67 > m45 ? m67 : m45;
            u64 best = m47 > m03 ? m47 : m03;
            int w0 = (NPTS - 1 - (int)(best & 0xFFFFFFFFull)) & (NPTS - 1);
            int w0s = __builtin_amdgcn_readfirstlane(w0);
            lx = pb[w0s * 3 + 0]; ly = pb[w0s * 3 + 1]; lz = pb[w0s * 3 + 2];
            if (t == 0) { sidx[s] = w0s; sx[s] = lx; sy[s] = ly; sz[s] = lz; }
        }
        __syncthreads();
        for (int e = t; e < MPTS; e += 512) {
            int base = (b * MPTS + e) * 3;
            out_newp[base + 0] = sx[e];
            out_newp[base + 1] = sy[e];
            out_newp[base + 2] = sz[e];
            idx[b * MPTS + e] = sidx[e];
        }
    } else if (f1t != nullptr) {
        float* fT = (float*)smem_u;
        int blk = blockIdx.x - 4;
        int b = blk >> 8;
        int n0 = (blk & 255) << 5;
        int t = threadIdx.x;
        const float* fb = f + (size_t)b * CIN * NPTS;
        for (int e = t; e < CIN * 32; e += 512) {
            int k = e >> 5, j = e & 31;
            fT[e] = fb[(size_t)k * NPTS + n0 + j];
        }
        __syncthreads();
        int c = t & 255, jh = (t >> 8) << 4;
        float bias = conv1_b[c];
        float acc[16];
#pragma unroll
        for (int j = 0; j < 16; ++j) acc[j] = bias;
        const float4* wrow4 = (const float4*)(conv1_w + (size_t)c * CIN);
        const float4* fT4 = (const float4*)fT;
        for (int k4 = 0; k4 < 32; ++k4) {
            float4 wv = wrow4[k4];
#pragma unroll
            for (int sub = 0; sub < 4; ++sub) {
                float w = sub == 0 ? wv.x : sub == 1 ? wv.y : sub == 2 ? wv.z : wv.w;
                int k = k4 * 4 + sub;
                int base = (k * 32 + jh) >> 2;
                float4 a0 = fT4[base+0], a1 = fT4[base+1], a2 = fT4[base+2], a3 = fT4[base+3];
                acc[0]  = fmaf(w, a0.x, acc[0]);  acc[1]  = fmaf(w, a0.y, acc[1]);
                acc[2]  = fmaf(w, a0.z, acc[2]);  acc[3]  = fmaf(w, a0.w, acc[3]);
                acc[4]  = fmaf(w, a1.x, acc[4]);  acc[5]  = fmaf(w, a1.y, acc[5]);
                acc[6]  = fmaf(w, a1.z, acc[6]);  acc[7]  = fmaf(w, a1.w, acc[7]);
                acc[8]  = fmaf(w, a2.x, acc[8]);  acc[9]  = fmaf(w, a2.y, acc[9]);
                acc[10] = fmaf(w, a2.z, acc[10]); acc[11] = fmaf(w, a2.w, acc[11]);
                acc[12] = fmaf(w, a3.x, acc[12]); acc[13] = fmaf(w, a3.y, acc[13]);
                acc[14] = fmaf(w, a3.z, acc[14]); acc[15] = fmaf(w, a3.w, acc[15]);
            }
        }
        float* dst = f1t + ((size_t)b * NPTS + n0 + jh) * CO + c;
#pragma unroll
        for (int j = 0; j < 16; ++j) dst[(size_t)j * CO] = acc[j];
    }
}

__global__ __launch_bounds__(256) void k_f1(const float* __restrict__ f,
                                            const float* __restrict__ conv1_w,
                                            const float* __restrict__ conv1_b,
                                            float* __restrict__ f1t, int b0) {
    __shared__ __align__(16) float fT[CIN * 16];
    int blk = blockIdx.x;
    int bl = blk >> 9;
    int b = b0 + bl;
    int n0 = (blk & 511) << 4;
    int t = threadIdx.x;
    const float* fb = f + (size_t)b * CIN * NPTS;
    for (int e = t; e < CIN * 16; e += 256) {
        int k = e >> 4, j = e & 15;
        fT[e] = fb[(size_t)k * NPTS + n0 + j];
    }
    __syncthreads();
    int c = t;
    float bias = conv1_b[c];
    float acc[16];
#pragma unroll
    for (int j = 0; j < 16; ++j) acc[j] = bias;
    const float4* wrow4 = (const float4*)(conv1_w + (size_t)c * CIN);
    const float4* fT4 = (const float4*)fT;
    for (int k4 = 0; k4 < 32; ++k4) {
        float4 wv = wrow4[k4];
#pragma unroll
        for (int sub = 0; sub < 4; ++sub) {
            float w = sub == 0 ? wv.x : sub == 1 ? wv.y : sub == 2 ? wv.z : wv.w;
            int k = k4 * 4 + sub;
            float4 a0 = fT4[k*4+0], a1 = fT4[k*4+1], a2 = fT4[k*4+2], a3 = fT4[k*4+3];
            acc[0]  = fmaf(w, a0.x, acc[0]);  acc[1]  = fmaf(w, a0.y, acc[1]);
            acc[2]  = fmaf(w, a0.z, acc[2]);  acc[3]  = fmaf(w, a0.w, acc[3]);
            acc[4]  = fmaf(w, a1.x, acc[4]);  acc[5]  = fmaf(w, a1.y, acc[5]);
            acc[6]  = fmaf(w, a1.z, acc[6]);  acc[7]  = fmaf(w, a1.w, acc[7]);
            acc[8]  = fmaf(w, a2.x, acc[8]);  acc[9]  = fmaf(w, a2.y, acc[9]);
            acc[10] = fmaf(w, a2.z, acc[10]); acc[11] = fmaf(w, a2.w, acc[11]);
            acc[12] = fmaf(w, a3.x, acc[12]); acc[13] = fmaf(w, a3.y, acc[13]);
            acc[14] = fmaf(w, a3.z, acc[14]); acc[15] = fmaf(w, a3.w, acc[15]);
        }
    }
    float* dst = f1t + ((size_t)bl * NPTS + n0) * CO + c;
#pragma unroll
    for (int j = 0; j < 16; ++j) dst[(size_t)j * CO] = acc[j];
}

__global__ __launch_bounds__(256) void k_feat(
    const float* __restrict__ p, const float* __restrict__ f,
    const float* __restrict__ f1t,
    const float* __restrict__ skip_w,  const float* __restrict__ skip_b,
    const float* __restrict__ bn1_g, const float* __restrict__ bn1_b,
    const float* __restrict__ bn1_m, const float* __restrict__ bn1_v,
    const float* __restrict__ dirv,  const float* __restrict__ de_w1,
    const float* __restrict__ de_g,  const float* __restrict__ de_bb,
    const float* __restrict__ de_m,  const float* __restrict__ de_v,
    const float* __restrict__ de_w2, const float* __restrict__ de_b2,
    const int* __restrict__ idx,     float* __restrict__ out_f, int b0) {
    __shared__ float sdx[KS], sdy[KS], sdz[KS];
    __shared__ float ltm[ND], lfi[CIN], lh[HALF];
    __shared__ int swidx[4][KS];
    __shared__ int scnt[4];
    __shared__ int nb[KS], nbp[KS];

    int q = b0 * MPTS + blockIdx.x;
    int b = q >> 11;
    int bl = b - b0;
    int m = q & (MPTS - 1);
    int t = threadIdx.x, lane = t & 63, w = t >> 6;
    const float* pb = p + (size_t)b * NPTS * 3;
    int i0 = idx[q] & (NPTS - 1);
    float qx = pb[i0 * 3 + 0], qy = pb[i0 * 3 + 1], qz = pb[i0 * 3 + 2];
    const float R2 = 0.1f * 0.1f;

    int cnt = 0;
    int seg = w * 2048;
    for (int base = 0; base < 2048; base += 64) {
        int j = seg + base + lane;
        float dx = __fsub_rn(pb[j * 3 + 0], qx);
        float dy = __fsub_rn(pb[j * 3 + 1], qy);
        float dz = __fsub_rn(pb[j * 3 + 2], qz);
        float d2 = __fadd_rn(__fadd_rn(__fmul_rn(dx, dx), __fmul_rn(dy, dy)),
                             __fmul_rn(dz, dz));
        bool hit = d2 < R2;
        u64 mask = __ballot(hit);
        if (hit) {
            int pos = cnt + __popcll(mask & ((1ull << lane) - 1ull));
            if (pos < KS) swidx[w][pos] = j;
        }
        cnt += __popcll(mask);
        if (cnt >= KS) break;
    }
    if (lane == 0) scnt[w] = cnt < KS ? cnt : KS;
    __syncthreads();
    int c0s = scnt[0], c1s = scnt[1], c2s = scnt[2], c3s = scnt[3];
    int st1 = c0s, st2 = c0s + c1s, st3 = c0s + c1s + c2s;
    int total = c0s + c1s + c2s + c3s; if (total > KS) total = KS;
    if (total < 1) total = 1;
    if (t < 128) {
        int ww = t >> 5, l = t & 31;
        int stw = (ww == 0) ? 0 : (ww == 1) ? st1 : (ww == 2) ? st2 : st3;
        int cw  = (ww == 0) ? c0s : (ww == 1) ? c1s : (ww == 2) ? c2s : c3s;
        int gp = stw + l;
        if (l < cw && gp < KS) nb[gp] = swidx[ww][l];
    }
    __syncthreads();
    if (t < KS) {
        int jk = nb[t < total ? t : 0] & (NPTS - 1);
        nbp[t] = jk;
        float dx = pb[jk * 3 + 0] - qx;
        float dy = pb[jk * 3 + 1] - qy;
        float dz = pb[jk * 3 + 2] - qz;
        float nr = fmaxf(sqrtf(dx * dx + dy * dy + dz * dz), 1e-12f);
        sdx[t] = dx / nr; sdy[t] = dy / nr; sdz[t] = dz / nr;
    }
    if (t >= 128) {
        lfi[t - 128] = f[((size_t)b * CIN + (t - 128)) * NPTS + i0];
    }
    __syncthreads();
    if (t < ND) {
        float ax = dirv[t * 3], ay = dirv[t * 3 + 1], az = dirv[t * 3 + 2];
        float n = fmaxf(sqrtf(ax * ax + ay * ay + az * az), 1e-12f);
        float vx = ax / n, vy = ay / n, vz = az / n;
        float tm = -1e30f;
#pragma unroll
        for (int k = 0; k < KS; ++k)
            tm = fmaxf(tm, vx * sdx[k] + vy * sdy[k] + vz * sdz[k]);
        ltm[t] = tm;
    }
    __syncthreads();

    int c = t;
    const float* f1b = f1t + (size_t)bl * NPTS * CO + c;
    float mx = -1e30f;
#pragma unroll 8
    for (int k = 0; k < KS; ++k) {
        mx = fmaxf(mx, f1b[(size_t)nbp[k] * CO]);
    }
    float sc1 = bn1_g[c] / sqrtf(bn1_v[c] + 1e-5f);
    float o1 = (mx - bn1_m[c]) * sc1 + bn1_b[c];

    float idv = skip_b[c];
    {
        const float4* sr = (const float4*)(skip_w + (size_t)c * CIN);
#pragma unroll 8
        for (int r = 0; r < 32; ++r) {
            float4 v = sr[r];
            idv = fmaf(v.x, lfi[r*4+0], fmaf(v.y, lfi[r*4+1],
                  fmaf(v.z, lfi[r*4+2], fmaf(v.w, lfi[r*4+3], idv))));
        }
    }
    {
        int hc = c & (HALF - 1);
        const float4* d1 = (const float4*)(de_w1 + (size_t)hc * ND);
        float a = 0.0f;
#pragma unroll
        for (int r = 0; r < 8; ++r) {
            float4 v = d1[r];
            a = fmaf(v.x, ltm[r*4+0], fmaf(v.y, ltm[r*4+1],
                fmaf(v.z, ltm[r*4+2], fmaf(v.w, ltm[r*4+3], a))));
        }
        float dsc = de_g[hc] / sqrtf(de_v[hc] + 1e-5f);
        float xb = (a - de_m[hc]) * dsc + de_bb[hc];
        float hv = 0.5f * xb * (1.0f + erff(xb * 0.70710678118654752440f));
        if (c < HALF) lh[c] = hv;
    }
    __syncthreads();
    float pe = de_b2[c];
    {
        const float4* d2p = (const float4*)(de_w2 + (size_t)c * HALF);
#pragma unroll 8
        for (int r = 0; r < 32; ++r) {
            float4 v = d2p[r];
            pe = fmaf(v.x, lh[r*4+0], fmaf(v.y, lh[r*4+1],
                 fmaf(v.z, lh[r*4+2], fmaf(v.w, lh[r*4+3], pe))));
        }
    }
    out_f[((size_t)b * CO + c) * MPTS + m] = o1 + pe + idv;
}

__global__ __launch_bounds__(256) void k_featz_fused(
    const float* __restrict__ p, const float* __restrict__ f,
    const float* __restrict__ conv1_w, const float* __restrict__ conv1_b,
    const float* __restrict__ skip_w,  const float* __restrict__ skip_b,
    const float* __restrict__ bn1_g, const float* __restrict__ bn1_b,
    const float* __restrict__ bn1_m, const float* __restrict__ bn1_v,
    const float* __restrict__ dirv,  const float* __restrict__ de_w1,
    const float* __restrict__ de_g,  const float* __restrict__ de_bb,
    const float* __restrict__ de_m,  const float* __restrict__ de_v,
    const float* __restrict__ de_w2, const float* __restrict__ de_b2,
    const int* __restrict__ idx,     float* __restrict__ out_f) {
    __shared__ __align__(16) float fg[KS * CIN];
    __shared__ float sdx[KS], sdy[KS], sdz[KS];
    __shared__ float ltm[ND], lfi[CIN], lh[HALF];
    __shared__ int swidx[4][KS];
    __shared__ int scnt[4];
    __shared__ int nb[KS], nbp[KS];

    int q = blockIdx.x;
    int b = q >> 11;
    int m = q & (MPTS - 1);
    int t = threadIdx.x, lane = t & 63, w = t >> 6;
    const float* pb = p + (size_t)b * NPTS * 3;
    int i0 = idx[q] & (NPTS - 1);
    float qx = pb[i0 * 3 + 0], qy = pb[i0 * 3 + 1], qz = pb[i0 * 3 + 2];
    const float R2 = 0.1f * 0.1f;
    int cnt = 0;
    int seg = w * 2048;
    for (int base = 0; base < 2048; base += 64) {
        int j = seg + base + lane;
        float dx = __fsub_rn(pb[j * 3 + 0], qx);
        float dy = __fsub_rn(pb[j * 3 + 1], qy);
        float dz = __fsub_rn(pb[j * 3 + 2], qz);
        float d2 = __fadd_rn(__fadd_rn(__fmul_rn(dx, dx), __fmul_rn(dy, dy)),
                             __fmul_rn(dz, dz));
        bool hit = d2 < R2;
        u64 mask = __ballot(hit);
        if (hit) {
            int pos = cnt + __popcll(mask & ((1ull << lane) - 1ull));
            if (pos < KS) swidx[w][pos] = j;
        }
        cnt += __popcll(mask);
        if (cnt >= KS) break;
    }
    if (lane == 0) scnt[w] = cnt < KS ? cnt : KS;
    __syncthreads();
    int c0s = scnt[0], c1s = scnt[1], c2s = scnt[2], c3s = scnt[3];
    int st1 = c0s, st2 = c0s + c1s, st3 = c0s + c1s + c2s;
    int total = c0s + c1s + c2s + c3s; if (total > KS) total = KS;
    if (total < 1) total = 1;
    if (t < 128) {
        int ww = t >> 5, l = t & 31;
        int stw = (ww == 0) ? 0 : (ww == 1) ? st1 : (ww == 2) ? st2 : st3;
        int cw  = (ww == 0) ? c0s : (ww == 1) ? c1s : (ww == 2) ? c2s : c3s;
        int gp = stw + l;
        if (l < cw && gp < KS) nb[gp] = swidx[ww][l];
    }
    __syncthreads();
    if (t < KS) {
        int jk = nb[t < total ? t : 0] & (NPTS - 1);
        nbp[t] = jk;
        float dx = pb[jk * 3 + 0] - qx;
        float dy = pb[jk * 3 + 1] - qy;
        float dz = pb[jk * 3 + 2] - qz;
        float nr = fmaxf(sqrtf(dx * dx + dy * dy + dz * dz), 1e-12f);
        sdx[t] = dx / nr; sdy[t] = dy / nr; sdz[t] = dz / nr;
    }
    if (t >= 128) lfi[t - 128] = f[((size_t)b * CIN + (t - 128)) * NPTS + i0];
    __syncthreads();
    if (t < ND) {
        float ax = dirv[t * 3], ay = dirv[t * 3 + 1], az = dirv[t * 3 + 2];
        float n = fmaxf(sqrtf(ax * ax + ay * ay + az * az), 1e-12f);
        float vx = ax / n, vy = ay / n, vz = az / n;
        float tm = -1e30f;
#pragma unroll
        for (int k = 0; k < KS; ++k)
            tm = fmaxf(tm, vx * sdx[k] + vy * sdy[k] + vz * sdz[k]);
        ltm[t] = tm;
    }
    for (int e = t; e < KS * CIN; e += 256) {
        int k = e >> 7, i = e & 127;
        fg[k * CIN + i] = f[((size_t)b * CIN + i) * NPTS + nbp[k]];
    }
    __syncthreads();
    int c = t;
    float acc[KS];
#pragma unroll
    for (int k = 0; k < KS; ++k) acc[k] = 0.0f;
    const float4* w4 = (const float4*)(conv1_w + (size_t)c * CIN);
    const float4* fg4 = (const float4*)fg;
    for (int i4 = 0; i4 < 32; ++i4) {
        float4 wv = w4[i4];
#pragma unroll 8
        for (int k = 0; k < KS; ++k) {
            float4 g = fg4[k * 32 + i4];
            acc[k] = fmaf(wv.x, g.x, fmaf(wv.y, g.y,
                     fmaf(wv.z, g.z, fmaf(wv.w, g.w, acc[k]))));
        }
    }
    float bias = conv1_b[c];
    float mx = -1e30f;
#pragma unroll
    for (int k = 0; k < KS; ++k) mx = fmaxf(mx, acc[k] + bias);
    float sc1 = bn1_g[c] / sqrtf(bn1_v[c] + 1e-5f);
    float o1 = (mx - bn1_m[c]) * sc1 + bn1_b[c];
    float idv = skip_b[c];
    {
        const float4* sr = (const float4*)(skip_w + (size_t)c * CIN);
#pragma unroll 8
        for (int r = 0; r < 32; ++r) {
            float4 v = sr[r];
            idv = fmaf(v.x, lfi[r*4+0], fmaf(v.y, lfi[r*4+1],
                  fmaf(v.z, lfi[r*4+2], fmaf(v.w, lfi[r*4+3], idv))));
        }
    }
    {
        int hc = c & (HALF - 1);
        const float4* d1 = (const float4*)(de_w1 + (size_t)hc * ND);
        float a = 0.0f;
#pragma unroll
        for (int r = 0; r < 8; ++r) {
            float4 v = d1[r];
            a = fmaf(v.x, ltm[r*4+0], fmaf(v.y, ltm[r*4+1],
                fmaf(v.z, ltm[r*4+2], fmaf(v.w, ltm[r*4+3], a))));
        }
        float dsc = de_g[hc] / sqrtf(de_v[hc] + 1e-5f);
        float xb = (a - de_m[hc]) * dsc + de_bb[hc];
        float hv = 0.5f * xb * (1.0f + erff(xb * 0.70710678118654752440f));
        if (c < HALF) lh[c] = hv;
    }
    __syncthreads();
    float pe = de_b2[c];
    {
        const float4* d2p = (const float4*)(de_w2 + (size_t)c * HALF);
#pragma unroll 8
        for (int r = 0; r < 32; ++r) {
            float4 v = d2p[r];
            pe = fmaf(v.x, lh[r*4+0], fmaf(v.y, lh[r*4+1],
                 fmaf(v.z, lh[r*4+2], fmaf(v.w, lh[r*4+3], pe))));
        }
    }
    out_f[((size_t)b * CO + c) * MPTS + m] = o1 + pe + idv;
}

extern "C" void kernel_launch(void* const* d_in, const int* in_sizes, int n_in,
                              void* d_out, int out_size, void* d_ws, size_t ws_size,
                              hipStream_t stream) {
    const float* p       = (const float*)d_in[0];
    const float* f       = (const float*)d_in[1];
    const float* conv1_w = (const float*)d_in[2];
    const float* conv1_b = (const float*)d_in[3];
    const float* skip_w  = (const float*)d_in[4];
    const float* skip_b  = (const float*)d_in[5];
    const float* bn1_g   = (const float*)d_in[6];
    const float* bn1_b   = (const float*)d_in[7];
    const float* bn1_m   = (const float*)d_in[8];
    const float* bn1_v   = (const float*)d_in[9];
    const float* dirv    = (const float*)d_in[10];
    const float* de_w1   = (const float*)d_in[11];
    const float* de_g    = (const float*)d_in[12];
    const float* de_bb   = (const float*)d_in[13];
    const float* de_m    = (const float*)d_in[14];
    const float* de_v    = (const float*)d_in[15];
    const float* de_w2   = (const float*)d_in[16];
    const float* de_b2   = (const float*)d_in[17];

    float* out_newp = (float*)d_out;
    float* out_f    = (float*)d_out + (size_t)BATCH * MPTS * 3;
    int*   idx      = (int*)d_ws;                         // 32 KB

    size_t f1_one  = (size_t)NPTS * CO * 4;               // 8 MB per batch
    size_t need_stream = 32768 + 128 + 4 * f1_one;
    size_t need_full   = 32768 + 4 * f1_one;
    size_t need_one    = 32768 + f1_one;

    if (ws_size >= need_stream) {
        int*   prog  = (int*)((char*)d_ws + 32768);       // [4]
        int*   f1all = prog + 4;
        float* f1t   = (float*)((char*)d_ws + 32768 + 128);
        hipMemsetAsync(prog, 0, 128, stream);
        k_mega<<<dim3(4 + 1024 + 4096), dim3(512), 0, stream>>>(
            p, f, conv1_w, conv1_b, skip_w, skip_b, bn1_g, bn1_b, bn1_m, bn1_v,
            dirv, de_w1, de_g, de_bb, de_m, de_v, de_w2, de_b2,
            out_newp, out_f, idx, f1t, prog, f1all);
    } else if (ws_size >= need_full) {
        float* f1t = (float*)((char*)d_ws + 32768);
        k_fps_f1<<<dim3(4 + 1024), dim3(512), 0, stream>>>(
            p, f, conv1_w, conv1_b, out_newp, idx, f1t);
        k_feat<<<dim3(4 * MPTS), dim3(256), 0, stream>>>(
            p, f, f1t, skip_w, skip_b, bn1_g, bn1_b, bn1_m, bn1_v,
            dirv, de_w1, de_g, de_bb, de_m, de_v, de_w2, de_b2, idx, out_f, 0);
    } else if (ws_size >= need_one) {
        float* f1t = (float*)((char*)d_ws + 32768);
        k_fps_f1<<<dim3(4), dim3(512), 0, stream>>>(
            p, f, conv1_w, conv1_b, out_newp, idx, nullptr);
        for (int b0 = 0; b0 < BATCH; ++b0) {
            k_f1  <<<dim3(512),  dim3(256), 0, stream>>>(f, conv1_w, conv1_b, f1t, b0);
            k_feat<<<dim3(MPTS), dim3(256), 0, stream>>>(
                p, f, f1t, skip_w, skip_b, bn1_g, bn1_b, bn1_m, bn1_v,
                dirv, de_w1, de_g, de_bb, de_m, de_v, de_w2, de_b2, idx, out_f, b0);
        }
    } else {
        k_fps_f1<<<dim3(4), dim3(512), 0, stream>>>(
            p, f, conv1_w, conv1_b, out_newp, idx, nullptr);
        k_featz_fused<<<dim3(BATCH * MPTS), dim3(256), 0, stream>>>(
            p, f, conv1_w, conv1_b, skip_w, skip_b, bn1_g, bn1_b, bn1_m, bn1_v,
            dirv, de_w1, de_g, de_bb, de_m, de_v, de_w2, de_b2, idx, out_f);
    }
}

// Round 9
// 2506.832 us; speedup vs baseline: 1.0204x; 1.0204x over previous
//
#include <hip/hip_runtime.h>

#define BATCH 4
#define NPTS 8192
#define MPTS 2048
#define CIN 128
#define CO 256
#define KS 32
#define ND 32
#define HALF 128

typedef unsigned int u32;
typedef unsigned long long u64;
typedef float f32x2 __attribute__((ext_vector_type(2)));

// DPP ctrl codes
#define DPPC_QUAD_XOR1 0xB1
#define DPPC_QUAD_XOR2 0x4E
#define DPPC_ROW_MIRROR 0x140
#define DPPC_ROW_HALF_MIRROR 0x141
#define DPPC_ROW_BCAST15 0x142
#define DPPC_ROW_BCAST31 0x143

template<int CTRL>
__device__ __forceinline__ float dpp_max(float v) {
    int o = __builtin_amdgcn_update_dpp(__float_as_int(-1e30f), __float_as_int(v),
                                        CTRL, 0xF, 0xF, false);
    return fmaxf(v, __int_as_float(o));
}
__device__ __forceinline__ float wave_max_f32(float v) {
    v = dpp_max<DPPC_QUAD_XOR1>(v);
    v = dpp_max<DPPC_QUAD_XOR2>(v);
    v = dpp_max<DPPC_ROW_HALF_MIRROR>(v);
    v = dpp_max<DPPC_ROW_MIRROR>(v);
    v = dpp_max<DPPC_ROW_BCAST15>(v);
    v = dpp_max<DPPC_ROW_BCAST31>(v);
    return __int_as_float(__builtin_amdgcn_readlane(__float_as_int(v), 63));
}

// packed fp32 (VOP3P): per-component IEEE ops -> bit-identical to scalar
__device__ __forceinline__ f32x2 pk_add(f32x2 a, f32x2 b) {
    f32x2 r;
    asm("v_pk_add_f32 %0, %1, %2" : "=v"(r) : "v"(a), "v"(b));
    return r;
}
__device__ __forceinline__ f32x2 pk_mul(f32x2 a, f32x2 b) {
    f32x2 r;
    asm("v_pk_mul_f32 %0, %1, %2" : "=v"(r) : "v"(a), "v"(b));
    return r;
}

struct FeatSmem {
    float sdx[KS], sdy[KS], sdz[KS];
    float ltm[ND], lfi[CIN], lh[HALF];
    int swidx[4][KS];
    int scnt[4];
    int nb[KS], nbp[KS];
};

// =================== streaming mega-kernel (mode 3, proven R7) =================
// blocks 0..3: FPS + per-step progress publish (agent-scope atomics).
//   R9 change: winner-coord extraction moved to the ISSUE side (R8 proved
//   >=250cyc issue slack): track (bx,by,bz) with the same g0/g1 cndmask as bi
//   during the dist loop; winner lane publishes {key}+{x,y,z} to LDS; reduce
//   tree tracks ww; coords come from ONE ds_read_b128 (~120cy) instead of the
//   per-step dependent s_load K$ miss (~300-500cy on the serial tail).
// blocks 4..1027: f1 precompute + completion publish.
// blocks 1028..5123: feat, 2 queries/block, spin-wait then acquire.
__global__
__attribute__((amdgpu_flat_work_group_size(512, 512), amdgpu_waves_per_eu(2, 2)))
void k_mega(
    const float* __restrict__ p, const float* __restrict__ f,
    const float* __restrict__ conv1_w, const float* __restrict__ conv1_b,
    const float* __restrict__ skip_w,  const float* __restrict__ skip_b,
    const float* __restrict__ bn1_g, const float* __restrict__ bn1_b,
    const float* __restrict__ bn1_m, const float* __restrict__ bn1_v,
    const float* __restrict__ dirv,  const float* __restrict__ de_w1,
    const float* __restrict__ de_g,  const float* __restrict__ de_bb,
    const float* __restrict__ de_m,  const float* __restrict__ de_v,
    const float* __restrict__ de_w2, const float* __restrict__ de_b2,
    float* __restrict__ out_newp, float* __restrict__ out_f,
    int* __restrict__ idx, float* __restrict__ f1t,
    int* prog, int* f1all) {
    __shared__ __align__(16) char smem_u[16640];
    if (blockIdx.x < 4) {
        // ---------------- FPS ----------------
        u64*    wkey = (u64*)smem_u;               // [2][8], 128 B
        float4* wxyz = (float4*)(smem_u + 128);    // [2][8], 256 B
        int b = blockIdx.x, t = threadIdx.x;
        int lane = t & 63, wid = t >> 6;
        int j0 = t * 16;
        const float* pb = p + (size_t)b * NPTS * 3;
        const float* pt = pb + t * 48;
        float px[16], py[16], pz[16];
#pragma unroll
        for (int c = 0; c < 4; ++c) {
            float4 q0 = *(const float4*)(pt + c * 12 + 0);
            float4 q1 = *(const float4*)(pt + c * 12 + 4);
            float4 q2 = *(const float4*)(pt + c * 12 + 8);
            px[c*4+0] = q0.x; py[c*4+0] = q0.y; pz[c*4+0] = q0.z;
            px[c*4+1] = q0.w; py[c*4+1] = q1.x; pz[c*4+1] = q1.y;
            px[c*4+2] = q1.z; py[c*4+2] = q1.w; pz[c*4+2] = q2.x;
            px[c*4+3] = q2.y; py[c*4+3] = q2.z; pz[c*4+3] = q2.w;
        }
        // pack into pairs (one-time) and pin -- packed ops need pair regs
        f32x2 px2[8], py2[8], pz2[8], dist2[8];
#pragma unroll
        for (int i = 0; i < 8; ++i) {
            px2[i].x = px[2*i]; px2[i].y = px[2*i+1];
            py2[i].x = py[2*i]; py2[i].y = py[2*i+1];
            pz2[i].x = pz[2*i]; pz2[i].y = pz[2*i+1];
        }
#pragma unroll
        for (int i = 0; i < 8; ++i) {
            asm volatile("" : "+v"(px2[i]), "+v"(py2[i]), "+v"(pz2[i]));
        }
#pragma unroll
        for (int i = 0; i < 8; ++i) { dist2[i].x = 1e10f; dist2[i].y = 1e10f; }
        float lx = pb[0], ly = pb[1], lz = pb[2];
        if (t == 0) {
            out_newp[(size_t)b * MPTS * 3 + 0] = lx;
            out_newp[(size_t)b * MPTS * 3 + 1] = ly;
            out_newp[(size_t)b * MPTS * 3 + 2] = lz;
            __hip_atomic_store(idx + b * MPTS, 0, __ATOMIC_RELAXED,
                               __HIP_MEMORY_SCOPE_AGENT);
        }
        for (int s = 1; s < MPTS; ++s) {
            int par = s & 1;
            // negated broadcast: px + (-lx) is IEEE-identical to px - lx
            f32x2 nlx2, nly2, nlz2;
            nlx2.x = -lx; nlx2.y = -lx;
            nly2.x = -ly; nly2.y = -ly;
            nlz2.x = -lz; nlz2.y = -lz;
            float bv = -1e30f; int bi = 0;
            float bx = px2[0].x, by = py2[0].x, bz = pz2[0].x;
#pragma unroll
            for (int i = 0; i < 8; ++i) {
                // numpy-f32 order: (dx*dx + dy*dy) + dz*dz, per-component
                f32x2 dx = pk_add(px2[i], nlx2);
                f32x2 dy = pk_add(py2[i], nly2);
                f32x2 dz = pk_add(pz2[i], nlz2);
                f32x2 d  = pk_add(pk_add(pk_mul(dx, dx), pk_mul(dy, dy)),
                                  pk_mul(dz, dz));
                float nd0 = fminf(dist2[i].x, d.x);
                float nd1 = fminf(dist2[i].y, d.y);
                dist2[i].x = nd0;
                dist2[i].y = nd1;
                bool g0 = nd0 > bv;            // strict > keeps lowest index
                bi = g0 ? 2*i : bi;
                bx = g0 ? px2[i].x : bx;       // issue-side tracking (R8: free)
                by = g0 ? py2[i].x : by;
                bz = g0 ? pz2[i].x : bz;
                bv = fmaxf(bv, nd0);
                bool g1 = nd1 > bv;
                bi = g1 ? 2*i+1 : bi;
                bx = g1 ? px2[i].y : bx;
                by = g1 ? py2[i].y : by;
                bz = g1 ? pz2[i].y : bz;
                bv = fmaxf(bv, nd1);
            }
            float gmw = wave_max_f32(bv);
            u64 mask = __ballot(bv == gmw);
            int first = __ffsll((long long)mask) - 1;
            if (lane == first) {
                wkey[par * 8 + wid] = ((u64)__float_as_uint(gmw) << 32)
                                    | (u64)(u32)(NPTS - 1 - (j0 + bi));
                wxyz[par * 8 + wid] = make_float4(bx, by, bz, 0.0f);
            }
            __syncthreads();                    // only barrier per step
            // pairwise tree with winner-wave tracking (ties prefer lower
            // wave via strict >; key encodes NPTS-1-j -> smallest j wins)
            const u64* wk = wkey + par * 8;
            u64 k0 = wk[0], k1 = wk[1], k2 = wk[2], k3 = wk[3];
            u64 k4 = wk[4], k5 = wk[5], k6 = wk[6], k7 = wk[7];
            u64 m01 = k1 > k0 ? k1 : k0;  int w01 = k1 > k0 ? 1 : 0;
            u64 m23 = k3 > k2 ? k3 : k2;  int w23 = k3 > k2 ? 3 : 2;
            u64 m45 = k5 > k4 ? k5 : k4;  int w45 = k5 > k4 ? 5 : 4;
            u64 m67 = k7 > k6 ? k7 : k6;  int w67 = k7 > k6 ? 7 : 6;
            u64 m03 = m23 > m01 ? m23 : m01; int w03 = m23 > m01 ? w23 : w01;
            u64 m47 = m67 > m45 ? m67 : m45; int w47 = m67 > m45 ? w67 : w45;
            u64 best = m47 > m03 ? m47 : m03; int ww = m47 > m03 ? w47 : w03;
            float4 wp = wxyz[par * 8 + ww];     // ds_read_b128, no K$ miss
            lx = wp.x; ly = wp.y; lz = wp.z;
            if (t == 0) {
                int w0 = (NPTS - 1 - (int)(best & 0xFFFFFFFFull)) & (NPTS - 1);
                // publish progress for steps < s; vmcnt(0) waits only
                // ~1-step-old acks (already retired) -> effectively free
                asm volatile("s_waitcnt vmcnt(0)" ::: "memory");
                __hip_atomic_store(prog + b, s, __ATOMIC_RELAXED,
                                   __HIP_MEMORY_SCOPE_AGENT);
                out_newp[((size_t)b * MPTS + s) * 3 + 0] = lx;
                out_newp[((size_t)b * MPTS + s) * 3 + 1] = ly;
                out_newp[((size_t)b * MPTS + s) * 3 + 2] = lz;
                __hip_atomic_store(idx + b * MPTS + s, w0, __ATOMIC_RELAXED,
                                   __HIP_MEMORY_SCOPE_AGENT);
            }
            // parity double-buffer: next same-parity write happens only after
            // the next barrier, i.e. after all reads here -> no second barrier.
        }
        if (t == 0) {
            asm volatile("s_waitcnt vmcnt(0)" ::: "memory");
            __hip_atomic_store(prog + b, MPTS, __ATOMIC_RELAXED,
                               __HIP_MEMORY_SCOPE_AGENT);
        }
    } else if (blockIdx.x < 4 + 1024) {
        // ---------------- f1 precompute ----------------
        float* fT = (float*)smem_u;            // [k][j], 16 KB
        int blk = blockIdx.x - 4;
        int b = blk >> 8;
        int n0 = (blk & 255) << 5;
        int t = threadIdx.x;
        const float* fb = f + (size_t)b * CIN * NPTS;
        for (int e = t; e < CIN * 32; e += 512) {
            int k = e >> 5, j = e & 31;
            fT[e] = fb[(size_t)k * NPTS + n0 + j];
        }
        __syncthreads();
        int c = t & 255, jh = (t >> 8) << 4;
        float bias = conv1_b[c];
        float acc[16];
#pragma unroll
        for (int j = 0; j < 16; ++j) acc[j] = bias;
        const float4* wrow4 = (const float4*)(conv1_w + (size_t)c * CIN);
        const float4* fT4 = (const float4*)fT;
        for (int k4 = 0; k4 < 32; ++k4) {
            float4 wv = wrow4[k4];
#pragma unroll
            for (int sub = 0; sub < 4; ++sub) {
                float w = sub == 0 ? wv.x : sub == 1 ? wv.y : sub == 2 ? wv.z : wv.w;
                int k = k4 * 4 + sub;
                int base = (k * 32 + jh) >> 2;
                float4 a0 = fT4[base+0], a1 = fT4[base+1], a2 = fT4[base+2], a3 = fT4[base+3];
                acc[0]  = fmaf(w, a0.x, acc[0]);  acc[1]  = fmaf(w, a0.y, acc[1]);
                acc[2]  = fmaf(w, a0.z, acc[2]);  acc[3]  = fmaf(w, a0.w, acc[3]);
                acc[4]  = fmaf(w, a1.x, acc[4]);  acc[5]  = fmaf(w, a1.y, acc[5]);
                acc[6]  = fmaf(w, a1.z, acc[6]);  acc[7]  = fmaf(w, a1.w, acc[7]);
                acc[8]  = fmaf(w, a2.x, acc[8]);  acc[9]  = fmaf(w, a2.y, acc[9]);
                acc[10] = fmaf(w, a2.z, acc[10]); acc[11] = fmaf(w, a2.w, acc[11]);
                acc[12] = fmaf(w, a3.x, acc[12]); acc[13] = fmaf(w, a3.y, acc[13]);
                acc[14] = fmaf(w, a3.z, acc[14]); acc[15] = fmaf(w, a3.w, acc[15]);
            }
        }
        float* dst = f1t + ((size_t)b * NPTS + n0 + jh) * CO + c;
#pragma unroll
        for (int j = 0; j < 16; ++j) dst[(size_t)j * CO] = acc[j];
        __syncthreads();                       // all block's stores ack'd
        if (t == 0) {
            __threadfence();                   // push to coherent point
            atomicAdd(f1all, 1);               // device-scope, cross-XCD safe
        }
    } else {
        // ---------------- streaming feat: 2 queries per block ----------------
        int fb = (int)blockIdx.x - (4 + 1024);
        int m  = fb >> 1;
        int bA = (fb & 1) * 2;
        int t = threadIdx.x;
        if (t == 0) {
            int need = m + 1;
            for (int it = 0; it < (1 << 21); ++it) {
                if (__hip_atomic_load(prog + bA, __ATOMIC_RELAXED,
                                      __HIP_MEMORY_SCOPE_AGENT) >= need) break;
                __builtin_amdgcn_s_sleep(127);
            }
            for (int it = 0; it < (1 << 21); ++it) {
                if (__hip_atomic_load(prog + bA + 1, __ATOMIC_RELAXED,
                                      __HIP_MEMORY_SCOPE_AGENT) >= need) break;
                __builtin_amdgcn_s_sleep(127);
            }
            for (int it = 0; it < (1 << 21); ++it) {
                if (__hip_atomic_load(f1all, __ATOMIC_RELAXED,
                                      __HIP_MEMORY_SCOPE_AGENT) >= 1024) break;
                __builtin_amdgcn_s_sleep(127);
            }
            (void)__hip_atomic_load(prog + bA, __ATOMIC_ACQUIRE,
                                    __HIP_MEMORY_SCOPE_AGENT);
        }
        __syncthreads();
        int qi = t >> 8;                       // 0 or 1
        int tq = t & 255;
        int b  = bA + qi;
        FeatSmem* fs = ((FeatSmem*)smem_u) + qi;
        int lane = t & 63, wq = (t >> 6) & 3;
        const float* pb = p + (size_t)b * NPTS * 3;
        int i0 = idx[(size_t)b * MPTS + m] & (NPTS - 1);
        float qx = pb[i0 * 3 + 0], qy = pb[i0 * 3 + 1], qz = pb[i0 * 3 + 2];
        const float R2 = 0.1f * 0.1f;

        int cnt = 0;
        int seg = wq * 2048;
        for (int base = 0; base < 2048; base += 64) {
            int j = seg + base + lane;
            float dx = __fsub_rn(pb[j * 3 + 0], qx);
            float dy = __fsub_rn(pb[j * 3 + 1], qy);
            float dz = __fsub_rn(pb[j * 3 + 2], qz);
            float d2 = __fadd_rn(__fadd_rn(__fmul_rn(dx, dx), __fmul_rn(dy, dy)),
                                 __fmul_rn(dz, dz));
            bool hit = d2 < R2;
            u64 mask = __ballot(hit);
            if (hit) {
                int pos = cnt + __popcll(mask & ((1ull << lane) - 1ull));
                if (pos < KS) fs->swidx[wq][pos] = j;
            }
            cnt += __popcll(mask);
            if (cnt >= KS) break;
        }
        if (lane == 0) fs->scnt[wq] = cnt < KS ? cnt : KS;
        __syncthreads();
        int c0s = fs->scnt[0], c1s = fs->scnt[1], c2s = fs->scnt[2], c3s = fs->scnt[3];
        int st1 = c0s, st2 = c0s + c1s, st3 = c0s + c1s + c2s;
        int total = c0s + c1s + c2s + c3s; if (total > KS) total = KS;
        if (total < 1) total = 1;
        if (tq < 128) {
            int ww = tq >> 5, l = tq & 31;
            int stw = (ww == 0) ? 0 : (ww == 1) ? st1 : (ww == 2) ? st2 : st3;
            int cw  = (ww == 0) ? c0s : (ww == 1) ? c1s : (ww == 2) ? c2s : c3s;
            int gp = stw + l;
            if (l < cw && gp < KS) fs->nb[gp] = fs->swidx[ww][l];
        }
        __syncthreads();
        if (tq < KS) {
            int jk = fs->nb[tq < total ? tq : 0] & (NPTS - 1);
            fs->nbp[tq] = jk;
            float dx = pb[jk * 3 + 0] - qx;
            float dy = pb[jk * 3 + 1] - qy;
            float dz = pb[jk * 3 + 2] - qz;
            float nr = fmaxf(sqrtf(dx * dx + dy * dy + dz * dz), 1e-12f);
            fs->sdx[tq] = dx / nr; fs->sdy[tq] = dy / nr; fs->sdz[tq] = dz / nr;
        }
        if (tq >= 128) {
            fs->lfi[tq - 128] = f[((size_t)b * CIN + (tq - 128)) * NPTS + i0];
        }
        __syncthreads();
        if (tq < ND) {
            float ax = dirv[tq * 3], ay = dirv[tq * 3 + 1], az = dirv[tq * 3 + 2];
            float n = fmaxf(sqrtf(ax * ax + ay * ay + az * az), 1e-12f);
            float vx = ax / n, vy = ay / n, vz = az / n;
            float tm = -1e30f;
#pragma unroll
            for (int k = 0; k < KS; ++k)
                tm = fmaxf(tm, vx * fs->sdx[k] + vy * fs->sdy[k] + vz * fs->sdz[k]);
            fs->ltm[tq] = tm;
        }
        __syncthreads();

        int c = tq;
        const float* f1b = f1t + (size_t)b * NPTS * CO + c;
        float mx = -1e30f;
#pragma unroll 8
        for (int k = 0; k < KS; ++k) {
            mx = fmaxf(mx, f1b[(size_t)fs->nbp[k] * CO]);
        }
        float sc1 = bn1_g[c] / sqrtf(bn1_v[c] + 1e-5f);
        float o1 = (mx - bn1_m[c]) * sc1 + bn1_b[c];

        float idv = skip_b[c];
        {
            const float4* sr = (const float4*)(skip_w + (size_t)c * CIN);
#pragma unroll 8
            for (int r = 0; r < 32; ++r) {
                float4 v = sr[r];
                idv = fmaf(v.x, fs->lfi[r*4+0], fmaf(v.y, fs->lfi[r*4+1],
                      fmaf(v.z, fs->lfi[r*4+2], fmaf(v.w, fs->lfi[r*4+3], idv))));
            }
        }
        {
            int hc = c & (HALF - 1);
            const float4* d1 = (const float4*)(de_w1 + (size_t)hc * ND);
            float a = 0.0f;
#pragma unroll
            for (int r = 0; r < 8; ++r) {
                float4 v = d1[r];
                a = fmaf(v.x, fs->ltm[r*4+0], fmaf(v.y, fs->ltm[r*4+1],
                    fmaf(v.z, fs->ltm[r*4+2], fmaf(v.w, fs->ltm[r*4+3], a))));
            }
            float dsc = de_g[hc] / sqrtf(de_v[hc] + 1e-5f);
            float xb = (a - de_m[hc]) * dsc + de_bb[hc];
            float hv = 0.5f * xb * (1.0f + erff(xb * 0.70710678118654752440f));
            if (c < HALF) fs->lh[c] = hv;
        }
        __syncthreads();
        float pe = de_b2[c];
        {
            const float4* d2p = (const float4*)(de_w2 + (size_t)c * HALF);
#pragma unroll 8
            for (int r = 0; r < 32; ++r) {
                float4 v = d2p[r];
                pe = fmaf(v.x, fs->lh[r*4+0], fmaf(v.y, fs->lh[r*4+1],
                     fmaf(v.z, fs->lh[r*4+2], fmaf(v.w, fs->lh[r*4+3], pe))));
            }
        }
        out_f[((size_t)b * CO + c) * MPTS + m] = o1 + pe + idv;
    }
}

// =================== fallback kernels (modes 2/1/0, unchanged) =================
__global__ __launch_bounds__(512, 2) void k_fps_f1(
    const float* __restrict__ p, const float* __restrict__ f,
    const float* __restrict__ conv1_w, const float* __restrict__ conv1_b,
    float* __restrict__ out_newp, int* __restrict__ idx,
    float* __restrict__ f1t) {
    __shared__ __align__(16) char smem_u[33024];
    if (blockIdx.x < 4) {
        u64*   wkey = (u64*)smem_u;
        int*   sidx = (int*)(smem_u + 128);
        float* sx   = (float*)(smem_u + 128 + 4 * MPTS);
        float* sy   = sx + MPTS;
        float* sz   = sy + MPTS;
        int b = blockIdx.x, t = threadIdx.x;
        int lane = t & 63, wid = t >> 6;
        int j0 = t * 16;
        const float* pb = p + (size_t)b * NPTS * 3;
        const float* pt = pb + t * 48;
        float px[16], py[16], pz[16], dist[16];
#pragma unroll
        for (int c = 0; c < 4; ++c) {
            float4 q0 = *(const float4*)(pt + c * 12 + 0);
            float4 q1 = *(const float4*)(pt + c * 12 + 4);
            float4 q2 = *(const float4*)(pt + c * 12 + 8);
            px[c*4+0] = q0.x; py[c*4+0] = q0.y; pz[c*4+0] = q0.z;
            px[c*4+1] = q0.w; py[c*4+1] = q1.x; pz[c*4+1] = q1.y;
            px[c*4+2] = q1.z; py[c*4+2] = q1.w; pz[c*4+2] = q2.x;
            px[c*4+3] = q2.y; py[c*4+3] = q2.z; pz[c*4+3] = q2.w;
        }
#pragma unroll
        for (int i = 0; i < 16; ++i) dist[i] = 1e10f;
        float lx = pb[0], ly = pb[1], lz = pb[2];
        if (t == 0) { sidx[0] = 0; sx[0] = lx; sy[0] = ly; sz[0] = lz; }
        for (int s = 1; s < MPTS; ++s) {
            int par = s & 1;
            float bv = -1e30f; int bi = 0;
#pragma unroll
            for (int i = 0; i < 16; ++i) {
                float dx = __fsub_rn(px[i], lx);
                float dy = __fsub_rn(py[i], ly);
                float dz = __fsub_rn(pz[i], lz);
                float d  = __fadd_rn(__fadd_rn(__fmul_rn(dx, dx), __fmul_rn(dy, dy)),
                                     __fmul_rn(dz, dz));
                float nd = fminf(dist[i], d);
                dist[i] = nd;
                bool gt = nd > bv;
                bi = gt ? i : bi;
                bv = fmaxf(bv, nd);
            }
            float gmw = wave_max_f32(bv);
            u64 mask = __ballot(bv == gmw);
            int first = __ffsll((long long)mask) - 1;
            if (lane == first) {
                wkey[par * 8 + wid] = ((u64)__float_as_uint(gmw) << 32)
                                    | (u64)(u32)(NPTS - 1 - (j0 + bi));
            }
            __syncthreads();
            const u64* wk = wkey + par * 8;
            u64 k0 = wk[0], k1 = wk[1], k2 = wk[2], k3 = wk[3];
            u64 k4 = wk[4], k5 = wk[5], k6 = wk[6], k7 = wk[7];
            u64 m01 = k1 > k0 ? k1 : k0;
            u64 m23 = k3 > k2 ? k3 : k2;
            u64 m45 = k5 > k4 ? k5 : k4;
            u64 m67 = k7 > k6 ? k7 : k6;
            u64 m03 = m23 > m01 ? m23 : m01;
            u64 m47 = m67 > m45 ? m67 : m45;
            u64 best = m47 > m03 ? m47 : m03;
            int w0 = (NPTS - 1 - (int)(best & 0xFFFFFFFFull)) & (NPTS - 1);
            int w0s = __builtin_amdgcn_readfirstlane(w0);
            lx = pb[w0s * 3 + 0]; ly = pb[w0s * 3 + 1]; lz = pb[w0s * 3 + 2];
            if (t == 0) { sidx[s] = w0s; sx[s] = lx; sy[s] = ly; sz[s] = lz; }
        }
        __syncthreads();
        for (int e = t; e < MPTS; e += 512) {
            int base = (b * MPTS + e) * 3;
            out_newp[base + 0] = sx[e];
            out_newp[base + 1] = sy[e];
            out_newp[base + 2] = sz[e];
            idx[b * MPTS + e] = sidx[e];
        }
    } else if (f1t != nullptr) {
        float* fT = (float*)smem_u;
        int blk = blockIdx.x - 4;
        int b = blk >> 8;
        int n0 = (blk & 255) << 5;
        int t = threadIdx.x;
        const float* fb = f + (size_t)b * CIN * NPTS;
        for (int e = t; e < CIN * 32; e += 512) {
            int k = e >> 5, j = e & 31;
            fT[e] = fb[(size_t)k * NPTS + n0 + j];
        }
        __syncthreads();
        int c = t & 255, jh = (t >> 8) << 4;
        float bias = conv1_b[c];
        float acc[16];
#pragma unroll
        for (int j = 0; j < 16; ++j) acc[j] = bias;
        const float4* wrow4 = (const float4*)(conv1_w + (size_t)c * CIN);
        const float4* fT4 = (const float4*)fT;
        for (int k4 = 0; k4 < 32; ++k4) {
            float4 wv = wrow4[k4];
#pragma unroll
            for (int sub = 0; sub < 4; ++sub) {
                float w = sub == 0 ? wv.x : sub == 1 ? wv.y : sub == 2 ? wv.z : wv.w;
                int k = k4 * 4 + sub;
                int base = (k * 32 + jh) >> 2;
                float4 a0 = fT4[base+0], a1 = fT4[base+1], a2 = fT4[base+2], a3 = fT4[base+3];
                acc[0]  = fmaf(w, a0.x, acc[0]);  acc[1]  = fmaf(w, a0.y, acc[1]);
                acc[2]  = fmaf(w, a0.z, acc[2]);  acc[3]  = fmaf(w, a0.w, acc[3]);
                acc[4]  = fmaf(w, a1.x, acc[4]);  acc[5]  = fmaf(w, a1.y, acc[5]);
                acc[6]  = fmaf(w, a1.z, acc[6]);  acc[7]  = fmaf(w, a1.w, acc[7]);
                acc[8]  = fmaf(w, a2.x, acc[8]);  acc[9]  = fmaf(w, a2.y, acc[9]);
                acc[10] = fmaf(w, a2.z, acc[10]); acc[11] = fmaf(w, a2.w, acc[11]);
                acc[12] = fmaf(w, a3.x, acc[12]); acc[13] = fmaf(w, a3.y, acc[13]);
                acc[14] = fmaf(w, a3.z, acc[14]); acc[15] = fmaf(w, a3.w, acc[15]);
            }
        }
        float* dst = f1t + ((size_t)b * NPTS + n0 + jh) * CO + c;
#pragma unroll
        for (int j = 0; j < 16; ++j) dst[(size_t)j * CO] = acc[j];
    }
}

__global__ __launch_bounds__(256) void k_f1(const float* __restrict__ f,
                                            const float* __restrict__ conv1_w,
                                            const float* __restrict__ conv1_b,
                                            float* __restrict__ f1t, int b0) {
    __shared__ __align__(16) float fT[CIN * 16];
    int blk = blockIdx.x;
    int bl = blk >> 9;
    int b = b0 + bl;
    int n0 = (blk & 511) << 4;
    int t = threadIdx.x;
    const float* fb = f + (size_t)b * CIN * NPTS;
    for (int e = t; e < CIN * 16; e += 256) {
        int k = e >> 4, j = e & 15;
        fT[e] = fb[(size_t)k * NPTS + n0 + j];
    }
    __syncthreads();
    int c = t;
    float bias = conv1_b[c];
    float acc[16];
#pragma unroll
    for (int j = 0; j < 16; ++j) acc[j] = bias;
    const float4* wrow4 = (const float4*)(conv1_w + (size_t)c * CIN);
    const float4* fT4 = (const float4*)fT;
    for (int k4 = 0; k4 < 32; ++k4) {
        float4 wv = wrow4[k4];
#pragma unroll
        for (int sub = 0; sub < 4; ++sub) {
            float w = sub == 0 ? wv.x : sub == 1 ? wv.y : sub == 2 ? wv.z : wv.w;
            int k = k4 * 4 + sub;
            float4 a0 = fT4[k*4+0], a1 = fT4[k*4+1], a2 = fT4[k*4+2], a3 = fT4[k*4+3];
            acc[0]  = fmaf(w, a0.x, acc[0]);  acc[1]  = fmaf(w, a0.y, acc[1]);
            acc[2]  = fmaf(w, a0.z, acc[2]);  acc[3]  = fmaf(w, a0.w, acc[3]);
            acc[4]  = fmaf(w, a1.x, acc[4]);  acc[5]  = fmaf(w, a1.y, acc[5]);
            acc[6]  = fmaf(w, a1.z, acc[6]);  acc[7]  = fmaf(w, a1.w, acc[7]);
            acc[8]  = fmaf(w, a2.x, acc[8]);  acc[9]  = fmaf(w, a2.y, acc[9]);
            acc[10] = fmaf(w, a2.z, acc[10]); acc[11] = fmaf(w, a2.w, acc[11]);
            acc[12] = fmaf(w, a3.x, acc[12]); acc[13] = fmaf(w, a3.y, acc[13]);
            acc[14] = fmaf(w, a3.z, acc[14]); acc[15] = fmaf(w, a3.w, acc[15]);
        }
    }
    float* dst = f1t + ((size_t)bl * NPTS + n0) * CO + c;
#pragma unroll
    for (int j = 0; j < 16; ++j) dst[(size_t)j * CO] = acc[j];
}

__global__ __launch_bounds__(256) void k_feat(
    const float* __restrict__ p, const float* __restrict__ f,
    const float* __restrict__ f1t,
    const float* __restrict__ skip_w,  const float* __restrict__ skip_b,
    const float* __restrict__ bn1_g, const float* __restrict__ bn1_b,
    const float* __restrict__ bn1_m, const float* __restrict__ bn1_v,
    const float* __restrict__ dirv,  const float* __restrict__ de_w1,
    const float* __restrict__ de_g,  const float* __restrict__ de_bb,
    const float* __restrict__ de_m,  const float* __restrict__ de_v,
    const float* __restrict__ de_w2, const float* __restrict__ de_b2,
    const int* __restrict__ idx,     float* __restrict__ out_f, int b0) {
    __shared__ float sdx[KS], sdy[KS], sdz[KS];
    __shared__ float ltm[ND], lfi[CIN], lh[HALF];
    __shared__ int swidx[4][KS];
    __shared__ int scnt[4];
    __shared__ int nb[KS], nbp[KS];

    int q = b0 * MPTS + blockIdx.x;
    int b = q >> 11;
    int bl = b - b0;
    int m = q & (MPTS - 1);
    int t = threadIdx.x, lane = t & 63, w = t >> 6;
    const float* pb = p + (size_t)b * NPTS * 3;
    int i0 = idx[q] & (NPTS - 1);
    float qx = pb[i0 * 3 + 0], qy = pb[i0 * 3 + 1], qz = pb[i0 * 3 + 2];
    const float R2 = 0.1f * 0.1f;

    int cnt = 0;
    int seg = w * 2048;
    for (int base = 0; base < 2048; base += 64) {
        int j = seg + base + lane;
        float dx = __fsub_rn(pb[j * 3 + 0], qx);
        float dy = __fsub_rn(pb[j * 3 + 1], qy);
        float dz = __fsub_rn(pb[j * 3 + 2], qz);
        float d2 = __fadd_rn(__fadd_rn(__fmul_rn(dx, dx), __fmul_rn(dy, dy)),
                             __fmul_rn(dz, dz));
        bool hit = d2 < R2;
        u64 mask = __ballot(hit);
        if (hit) {
            int pos = cnt + __popcll(mask & ((1ull << lane) - 1ull));
            if (pos < KS) swidx[w][pos] = j;
        }
        cnt += __popcll(mask);
        if (cnt >= KS) break;
    }
    if (lane == 0) scnt[w] = cnt < KS ? cnt : KS;
    __syncthreads();
    int c0s = scnt[0], c1s = scnt[1], c2s = scnt[2], c3s = scnt[3];
    int st1 = c0s, st2 = c0s + c1s, st3 = c0s + c1s + c2s;
    int total = c0s + c1s + c2s + c3s; if (total > KS) total = KS;
    if (total < 1) total = 1;
    if (t < 128) {
        int ww = t >> 5, l = t & 31;
        int stw = (ww == 0) ? 0 : (ww == 1) ? st1 : (ww == 2) ? st2 : st3;
        int cw  = (ww == 0) ? c0s : (ww == 1) ? c1s : (ww == 2) ? c2s : c3s;
        int gp = stw + l;
        if (l < cw && gp < KS) nb[gp] = swidx[ww][l];
    }
    __syncthreads();
    if (t < KS) {
        int jk = nb[t < total ? t : 0] & (NPTS - 1);
        nbp[t] = jk;
        float dx = pb[jk * 3 + 0] - qx;
        float dy = pb[jk * 3 + 1] - qy;
        float dz = pb[jk * 3 + 2] - qz;
        float nr = fmaxf(sqrtf(dx * dx + dy * dy + dz * dz), 1e-12f);
        sdx[t] = dx / nr; sdy[t] = dy / nr; sdz[t] = dz / nr;
    }
    if (t >= 128) {
        lfi[t - 128] = f[((size_t)b * CIN + (t - 128)) * NPTS + i0];
    }
    __syncthreads();
    if (t < ND) {
        float ax = dirv[t * 3], ay = dirv[t * 3 + 1], az = dirv[t * 3 + 2];
        float n = fmaxf(sqrtf(ax * ax + ay * ay + az * az), 1e-12f);
        float vx = ax / n, vy = ay / n, vz = az / n;
        float tm = -1e30f;
#pragma unroll
        for (int k = 0; k < KS; ++k)
            tm = fmaxf(tm, vx * sdx[k] + vy * sdy[k] + vz * sdz[k]);
        ltm[t] = tm;
    }
    __syncthreads();

    int c = t;
    const float* f1b = f1t + (size_t)bl * NPTS * CO + c;
    float mx = -1e30f;
#pragma unroll 8
    for (int k = 0; k < KS; ++k) {
        mx = fmaxf(mx, f1b[(size_t)nbp[k] * CO]);
    }
    float sc1 = bn1_g[c] / sqrtf(bn1_v[c] + 1e-5f);
    float o1 = (mx - bn1_m[c]) * sc1 + bn1_b[c];

    float idv = skip_b[c];
    {
        const float4* sr = (const float4*)(skip_w + (size_t)c * CIN);
#pragma unroll 8
        for (int r = 0; r < 32; ++r) {
            float4 v = sr[r];
            idv = fmaf(v.x, lfi[r*4+0], fmaf(v.y, lfi[r*4+1],
                  fmaf(v.z, lfi[r*4+2], fmaf(v.w, lfi[r*4+3], idv))));
        }
    }
    {
        int hc = c & (HALF - 1);
        const float4* d1 = (const float4*)(de_w1 + (size_t)hc * ND);
        float a = 0.0f;
#pragma unroll
        for (int r = 0; r < 8; ++r) {
            float4 v = d1[r];
            a = fmaf(v.x, ltm[r*4+0], fmaf(v.y, ltm[r*4+1],
                fmaf(v.z, ltm[r*4+2], fmaf(v.w, ltm[r*4+3], a))));
        }
        float dsc = de_g[hc] / sqrtf(de_v[hc] + 1e-5f);
        float xb = (a - de_m[hc]) * dsc + de_bb[hc];
        float hv = 0.5f * xb * (1.0f + erff(xb * 0.70710678118654752440f));
        if (c < HALF) lh[c] = hv;
    }
    __syncthreads();
    float pe = de_b2[c];
    {
        const float4* d2p = (const float4*)(de_w2 + (size_t)c * HALF);
#pragma unroll 8
        for (int r = 0; r < 32; ++r) {
            float4 v = d2p[r];
            pe = fmaf(v.x, lh[r*4+0], fmaf(v.y, lh[r*4+1],
                 fmaf(v.z, lh[r*4+2], fmaf(v.w, lh[r*4+3], pe))));
        }
    }
    out_f[((size_t)b * CO + c) * MPTS + m] = o1 + pe + idv;
}

__global__ __launch_bounds__(256) void k_featz_fused(
    const float* __restrict__ p, const float* __restrict__ f,
    const float* __restrict__ conv1_w, const float* __restrict__ conv1_b,
    const float* __restrict__ skip_w,  const float* __restrict__ skip_b,
    const float* __restrict__ bn1_g, const float* __restrict__ bn1_b,
    const float* __restrict__ bn1_m, const float* __restrict__ bn1_v,
    const float* __restrict__ dirv,  const float* __restrict__ de_w1,
    const float* __restrict__ de_g,  const float* __restrict__ de_bb,
    const float* __restrict__ de_m,  const float* __restrict__ de_v,
    const float* __restrict__ de_w2, const float* __restrict__ de_b2,
    const int* __restrict__ idx,     float* __restrict__ out_f) {
    __shared__ __align__(16) float fg[KS * CIN];
    __shared__ float sdx[KS], sdy[KS], sdz[KS];
    __shared__ float ltm[ND], lfi[CIN], lh[HALF];
    __shared__ int swidx[4][KS];
    __shared__ int scnt[4];
    __shared__ int nb[KS], nbp[KS];

    int q = blockIdx.x;
    int b = q >> 11;
    int m = q & (MPTS - 1);
    int t = threadIdx.x, lane = t & 63, w = t >> 6;
    const float* pb = p + (size_t)b * NPTS * 3;
    int i0 = idx[q] & (NPTS - 1);
    float qx = pb[i0 * 3 + 0], qy = pb[i0 * 3 + 1], qz = pb[i0 * 3 + 2];
    const float R2 = 0.1f * 0.1f;
    int cnt = 0;
    int seg = w * 2048;
    for (int base = 0; base < 2048; base += 64) {
        int j = seg + base + lane;
        float dx = __fsub_rn(pb[j * 3 + 0], qx);
        float dy = __fsub_rn(pb[j * 3 + 1], qy);
        float dz = __fsub_rn(pb[j * 3 + 2], qz);
        float d2 = __fadd_rn(__fadd_rn(__fmul_rn(dx, dx), __fmul_rn(dy, dy)),
                             __fmul_rn(dz, dz));
        bool hit = d2 < R2;
        u64 mask = __ballot(hit);
        if (hit) {
            int pos = cnt + __popcll(mask & ((1ull << lane) - 1ull));
            if (pos < KS) swidx[w][pos] = j;
        }
        cnt += __popcll(mask);
        if (cnt >= KS) break;
    }
    if (lane == 0) scnt[w] = cnt < KS ? cnt : KS;
    __syncthreads();
    int c0s = scnt[0], c1s = scnt[1], c2s = scnt[2], c3s = scnt[3];
    int st1 = c0s, st2 = c0s + c1s, st3 = c0s + c1s + c2s;
    int total = c0s + c1s + c2s + c3s; if (total > KS) total = KS;
    if (total < 1) total = 1;
    if (t < 128) {
        int ww = t >> 5, l = t & 31;
        int stw = (ww == 0) ? 0 : (ww == 1) ? st1 : (ww == 2) ? st2 : st3;
        int cw  = (ww == 0) ? c0s : (ww == 1) ? c1s : (ww == 2) ? c2s : c3s;
        int gp = stw + l;
        if (l < cw && gp < KS) nb[gp] = swidx[ww][l];
    }
    __syncthreads();
    if (t < KS) {
        int jk = nb[t < total ? t : 0] & (NPTS - 1);
        nbp[t] = jk;
        float dx = pb[jk * 3 + 0] - qx;
        float dy = pb[jk * 3 + 1] - qy;
        float dz = pb[jk * 3 + 2] - qz;
        float nr = fmaxf(sqrtf(dx * dx + dy * dy + dz * dz), 1e-12f);
        sdx[t] = dx / nr; sdy[t] = dy / nr; sdz[t] = dz / nr;
    }
    if (t >= 128) lfi[t - 128] = f[((size_t)b * CIN + (t - 128)) * NPTS + i0];
    __syncthreads();
    if (t < ND) {
        float ax = dirv[t * 3], ay = dirv[t * 3 + 1], az = dirv[t * 3 + 2];
        float n = fmaxf(sqrtf(ax * ax + ay * ay + az * az), 1e-12f);
        float vx = ax / n, vy = ay / n, vz = az / n;
        float tm = -1e30f;
#pragma unroll
        for (int k = 0; k < KS; ++k)
            tm = fmaxf(tm, vx * sdx[k] + vy * sdy[k] + vz * sdz[k]);
        ltm[t] = tm;
    }
    for (int e = t; e < KS * CIN; e += 256) {
        int k = e >> 7, i = e & 127;
        fg[k * CIN + i] = f[((size_t)b * CIN + i) * NPTS + nbp[k]];
    }
    __syncthreads();
    int c = t;
    float acc[KS];
#pragma unroll
    for (int k = 0; k < KS; ++k) acc[k] = 0.0f;
    const float4* w4 = (const float4*)(conv1_w + (size_t)c * CIN);
    const float4* fg4 = (const float4*)fg;
    for (int i4 = 0; i4 < 32; ++i4) {
        float4 wv = w4[i4];
#pragma unroll 8
        for (int k = 0; k < KS; ++k) {
            float4 g = fg4[k * 32 + i4];
            acc[k] = fmaf(wv.x, g.x, fmaf(wv.y, g.y,
                     fmaf(wv.z, g.z, fmaf(wv.w, g.w, acc[k]))));
        }
    }
    float bias = conv1_b[c];
    float mx = -1e30f;
#pragma unroll
    for (int k = 0; k < KS; ++k) mx = fmaxf(mx, acc[k] + bias);
    float sc1 = bn1_g[c] / sqrtf(bn1_v[c] + 1e-5f);
    float o1 = (mx - bn1_m[c]) * sc1 + bn1_b[c];
    float idv = skip_b[c];
    {
        const float4* sr = (const float4*)(skip_w + (size_t)c * CIN);
#pragma unroll 8
        for (int r = 0; r < 32; ++r) {
            float4 v = sr[r];
            idv = fmaf(v.x, lfi[r*4+0], fmaf(v.y, lfi[r*4+1],
                  fmaf(v.z, lfi[r*4+2], fmaf(v.w, lfi[r*4+3], idv))));
        }
    }
    {
        int hc = c & (HALF - 1);
        const float4* d1 = (const float4*)(de_w1 + (size_t)hc * ND);
        float a = 0.0f;
#pragma unroll
        for (int r = 0; r < 8; ++r) {
            float4 v = d1[r];
            a = fmaf(v.x, ltm[r*4+0], fmaf(v.y, ltm[r*4+1],
                fmaf(v.z, ltm[r*4+2], fmaf(v.w, ltm[r*4+3], a))));
        }
        float dsc = de_g[hc] / sqrtf(de_v[hc] + 1e-5f);
        float xb = (a - de_m[hc]) * dsc + de_bb[hc];
        float hv = 0.5f * xb * (1.0f + erff(xb * 0.70710678118654752440f));
        if (c < HALF) lh[c] = hv;
    }
    __syncthreads();
    float pe = de_b2[c];
    {
        const float4* d2p = (const float4*)(de_w2 + (size_t)c * HALF);
#pragma unroll 8
        for (int r = 0; r < 32; ++r) {
            float4 v = d2p[r];
            pe = fmaf(v.x, lh[r*4+0], fmaf(v.y, lh[r*4+1],
                 fmaf(v.z, lh[r*4+2], fmaf(v.w, lh[r*4+3], pe))));
        }
    }
    out_f[((size_t)b * CO + c) * MPTS + m] = o1 + pe + idv;
}

extern "C" void kernel_launch(void* const* d_in, const int* in_sizes, int n_in,
                              void* d_out, int out_size, void* d_ws, size_t ws_size,
                              hipStream_t stream) {
    const float* p       = (const float*)d_in[0];
    const float* f       = (const float*)d_in[1];
    const float* conv1_w = (const float*)d_in[2];
    const float* conv1_b = (const float*)d_in[3];
    const float* skip_w  = (const float*)d_in[4];
    const float* skip_b  = (const float*)d_in[5];
    const float* bn1_g   = (const float*)d_in[6];
    const float* bn1_b   = (const float*)d_in[7];
    const float* bn1_m   = (const float*)d_in[8];
    const float* bn1_v   = (const float*)d_in[9];
    const float* dirv    = (const float*)d_in[10];
    const float* de_w1   = (const float*)d_in[11];
    const float* de_g    = (const float*)d_in[12];
    const float* de_bb   = (const float*)d_in[13];
    const float* de_m    = (const float*)d_in[14];
    const float* de_v    = (const float*)d_in[15];
    const float* de_w2   = (const float*)d_in[16];
    const float* de_b2   = (const float*)d_in[17];

    float* out_newp = (float*)d_out;
    float* out_f    = (float*)d_out + (size_t)BATCH * MPTS * 3;
    int*   idx      = (int*)d_ws;                         // 32 KB

    size_t f1_one  = (size_t)NPTS * CO * 4;               // 8 MB per batch
    size_t need_stream = 32768 + 128 + 4 * f1_one;
    size_t need_full   = 32768 + 4 * f1_one;
    size_t need_one    = 32768 + f1_one;

    if (ws_size >= need_stream) {
        int*   prog  = (int*)((char*)d_ws + 32768);       // [4]
        int*   f1all = prog + 4;
        float* f1t   = (float*)((char*)d_ws + 32768 + 128);
        hipMemsetAsync(prog, 0, 128, stream);
        k_mega<<<dim3(4 + 1024 + 4096), dim3(512), 0, stream>>>(
            p, f, conv1_w, conv1_b, skip_w, skip_b, bn1_g, bn1_b, bn1_m, bn1_v,
            dirv, de_w1, de_g, de_bb, de_m, de_v, de_w2, de_b2,
            out_newp, out_f, idx, f1t, prog, f1all);
    } else if (ws_size >= need_full) {
        float* f1t = (float*)((char*)d_ws + 32768);
        k_fps_f1<<<dim3(4 + 1024), dim3(512), 0, stream>>>(
            p, f, conv1_w, conv1_b, out_newp, idx, f1t);
        k_feat<<<dim3(4 * MPTS), dim3(256), 0, stream>>>(
            p, f, f1t, skip_w, skip_b, bn1_g, bn1_b, bn1_m, bn1_v,
            dirv, de_w1, de_g, de_bb, de_m, de_v, de_w2, de_b2, idx, out_f, 0);
    } else if (ws_size >= need_one) {
        float* f1t = (float*)((char*)d_ws + 32768);
        k_fps_f1<<<dim3(4), dim3(512), 0, stream>>>(
            p, f, conv1_w, conv1_b, out_newp, idx, nullptr);
        for (int b0 = 0; b0 < BATCH; ++b0) {
            k_f1  <<<dim3(512),  dim3(256), 0, stream>>>(f, conv1_w, conv1_b, f1t, b0);
            k_feat<<<dim3(MPTS), dim3(256), 0, stream>>>(
                p, f, f1t, skip_w, skip_b, bn1_g, bn1_b, bn1_m, bn1_v,
                dirv, de_w1, de_g, de_bb, de_m, de_v, de_w2, de_b2, idx, out_f, b0);
        }
    } else {
        k_fps_f1<<<dim3(4), dim3(512), 0, stream>>>(
            p, f, conv1_w, conv1_b, out_newp, idx, nullptr);
        k_featz_fused<<<dim3(BATCH * MPTS), dim3(256), 0, stream>>>(
            p, f, conv1_w, conv1_b, skip_w, skip_b, bn1_g, bn1_b, bn1_m, bn1_v,
            dirv, de_w1, de_g, de_bb, de_m, de_v, de_w2, de_b2, idx, out_f);
    }
}